// Round 5
// baseline (7554.591 us; speedup 1.0000x reference)
//
#include <hip/hip_runtime.h>

#define B_   32
#define T_   2048
#define DIN  128
#define H_   256
#define DOUT 256

typedef float f32x4 __attribute__((ext_vector_type(4)));
typedef short bf16x8 __attribute__((ext_vector_type(8)));

__device__ __forceinline__ unsigned short f2bf(float f) {
  unsigned int u = __builtin_bit_cast(unsigned int, f);
  u += 0x7FFFu + ((u >> 16) & 1u);              // round-to-nearest-even
  return (unsigned short)(u >> 16);
}
// unpack bf16 slot q (0..3) from a uint2 (q0|q1<<16, q2|q3<<16)
__device__ __forceinline__ float bfq(uint2 v, int q) {
  unsigned int u = (q & 2) ? v.y : v.x;
  u = (q & 1) ? (u & 0xFFFF0000u) : (u << 16);
  return __builtin_bit_cast(float, u);
}
__device__ __forceinline__ float sigm(float x) {
  return __builtin_amdgcn_rcpf(1.f + __expf(-x));
}

// ---------------- Kernel 1: G = x @ W + b, packed for the scan's MFMA lanes.
// Block = 4 batches x 8 timesteps (32 rows) x 256 cols, grid.y = gate.
// Output layout (uint2 = 4 bf16 for q=0..3):
//   Gzr[(((t*2+blk)*2+gate)*16 + (w*2+nt))*64 + l]   gates z,r  (in d_out)
//   Gh [(((t*2+blk)   )*16 + (w*2+nt))*64 + l]       gate h     (in ws)
// where b = blk*16 + m, q = m&3, l = (m>>2)*16 + (col&15), w = col>>5,
// nt = (col>>4)&1  — exactly the mfma 16x16x32 C-fragment lane mapping.
__global__ __launch_bounds__(256) void k_gates(
    const float* __restrict__ x,
    const float* __restrict__ Wz, const float* __restrict__ Wr,
    const float* __restrict__ Wh,
    const float* __restrict__ bz, const float* __restrict__ br,
    const float* __restrict__ bh,
    uint2* __restrict__ Gzr, uint2* __restrict__ Gh)
{
  __shared__ __align__(16) float sx[32][DIN];
  const int gate = blockIdx.y;
  const float* W = (gate == 0) ? Wz : (gate == 1) ? Wr : Wh;
  const float* bias = (gate == 0) ? bz : (gate == 1) ? br : bh;
  const int tg = blockIdx.x & 255;   // t-group
  const int bg = blockIdx.x >> 8;    // b-group 0..7
  const int t0 = tg * 8, b0 = bg * 4;
  const int tid = threadIdx.x;

  // stage x rows: i = bi*8 + ti  ->  row R = (b0+bi)*T + t0+ti
  {
    const float4* x4 = (const float4*)x;
    float4* s4 = (float4*)&sx[0][0];
#pragma unroll
    for (int mm = 0; mm < 4; ++mm) {
      int idx = tid + 256 * mm;      // 0..1023
      int i = idx >> 5, c4 = idx & 31;
      int Ri = (b0 + (i >> 3)) * T_ + t0 + (i & 7);
      s4[idx] = x4[(size_t)Ri * 32 + c4];
    }
  }
  __syncthreads();

  const int j = tid;
  const float bj = bias[j];
  float acc[32];
#pragma unroll
  for (int i = 0; i < 32; ++i) acc[i] = 0.f;

#pragma unroll 2
  for (int k4 = 0; k4 < DIN / 4; ++k4) {
    float w0 = W[(size_t)(4 * k4 + 0) * H_ + j];
    float w1 = W[(size_t)(4 * k4 + 1) * H_ + j];
    float w2 = W[(size_t)(4 * k4 + 2) * H_ + j];
    float w3 = W[(size_t)(4 * k4 + 3) * H_ + j];
#pragma unroll
    for (int i = 0; i < 32; ++i) {
      float4 xv = *(const float4*)&sx[i][4 * k4];
      acc[i] = fmaf(xv.x, w0, acc[i]);
      acc[i] = fmaf(xv.y, w1, acc[i]);
      acc[i] = fmaf(xv.z, w2, acc[i]);
      acc[i] = fmaf(xv.w, w3, acc[i]);
    }
  }

  const int w = j >> 5, nt = (j >> 4) & 1;
  const int l = (bg & 3) * 16 + (j & 15);
  const int blk = bg >> 2;
#pragma unroll
  for (int ti = 0; ti < 8; ++ti) {
    int t = t0 + ti;
    unsigned int q0 = f2bf(acc[0 * 8 + ti] + bj);
    unsigned int q1 = f2bf(acc[1 * 8 + ti] + bj);
    unsigned int q2 = f2bf(acc[2 * 8 + ti] + bj);
    unsigned int q3 = f2bf(acc[3 * 8 + ti] + bj);
    uint2 v;
    v.x = q0 | (q1 << 16);
    v.y = q2 | (q3 << 16);
    if (gate < 2) {
      size_t idx = ((((size_t)t * 2 + blk) * 2 + gate) * 16 + (w * 2 + nt)) * 64 + l;
      Gzr[idx] = v;
    } else {
      size_t idx = (((size_t)t * 2 + blk) * 16 + (w * 2 + nt)) * 64 + l;
      Gh[idx] = v;
    }
  }
}

// ---------------- Kernel 2: MFMA GRU scan. 2 blocks x 16 batches. ----------
// 512 threads = 8 waves. Wave w owns H-cols [32w, 32w+32) (2 N-tiles) of all
// three U matrices as 48 register-resident bf16 B-fragments (192 VGPRs),
// consumed in place by v_mfma_f32_16x16x32_bf16. h / r*h tiles live in LDS
// (bf16, chunk-XOR swizzled); h-state + z stay in C-layout registers.
__global__ __launch_bounds__(512) void k_scan(
    const float* __restrict__ h0,
    const float* __restrict__ Uz, const float* __restrict__ Ur,
    const float* __restrict__ Uh,
    const uint2* __restrict__ Gzr, const uint2* __restrict__ Gh,
    float* __restrict__ hs)
{
  __shared__ __align__(16) unsigned short h_lds[16 * 256];
  __shared__ __align__(16) unsigned short rh_lds[16 * 256];

  const int blk = blockIdx.x;        // 0..1
  const int tid = threadIdx.x;
  const int w = tid >> 6;            // wave 0..7
  const int l = tid & 63;
  const int lr = l & 15;             // A-row / col-low selector
  const int lh = l >> 4;             // 0..3 (k-group / m-group)
  const int m_base = lh * 4;

  // ---- B fragments: fragU[gate][nt][kt]; lane holds U[k0..k0+8)[n] ----
  bf16x8 fragU[3][2][8];
  {
    const float* Us[3] = {Uz, Ur, Uh};
#pragma unroll
    for (int g = 0; g < 3; ++g) {
#pragma unroll
      for (int nt = 0; nt < 2; ++nt) {
        int n = w * 32 + nt * 16 + lr;
#pragma unroll
        for (int kt = 0; kt < 8; ++kt) {
          int k0 = kt * 32 + lh * 8;
          bf16x8 f;
#pragma unroll
          for (int e = 0; e < 8; ++e)
            f[e] = (short)f2bf(Us[g][(size_t)(k0 + e) * H_ + n]);
          fragU[g][nt][kt] = f;
        }
      }
    }
  }

  // ---- init h-state (C-layout registers) + h_lds (swizzled bf16) ----
  float hreg[2][4];
#pragma unroll
  for (int nt = 0; nt < 2; ++nt) {
    int n = w * 32 + nt * 16 + lr;
#pragma unroll
    for (int q = 0; q < 4; ++q) {
      int m = m_base + q;
      float h = h0[(size_t)(blk * 16 + m) * H_ + n];
      hreg[nt][q] = h;
      int byteoff = m * 512 + ((((n >> 3) ^ (m & 7)) << 4)) + (n & 7) * 2;
      h_lds[byteoff >> 1] = f2bf(h);
    }
  }
  __syncthreads();

  // ---- G: load t=0, prefetch one step ahead inside the loop ----
  const size_t gl0 = (size_t)(w * 2 + 0) * 64 + l;
  const size_t gl1 = (size_t)(w * 2 + 1) * 64 + l;
  uint2 gz0, gz1, gr0, gr1, gh0, gh1;
  {
    size_t bzr = ((size_t)0 * 2 + blk) * 2 * 1024;
    size_t bh = ((size_t)0 * 2 + blk) * 1024;
    gz0 = Gzr[bzr + gl0];        gz1 = Gzr[bzr + gl1];
    gr0 = Gzr[bzr + 1024 + gl0]; gr1 = Gzr[bzr + 1024 + gl1];
    gh0 = Gh[bh + gl0];          gh1 = Gh[bh + gl1];
  }

  float* hsb = hs + (size_t)(blk * 16) * T_ * H_;
  const f32x4 zero4 = {0.f, 0.f, 0.f, 0.f};

#pragma unroll 1
  for (int t = 0; t < T_; ++t) {
    // prefetch next step's G (independent of everything this step)
    uint2 ngz0, ngz1, ngr0, ngr1, ngh0, ngh1;
    {
      int tn = (t + 1 < T_) ? (t + 1) : t;
      size_t bzr = ((size_t)tn * 2 + blk) * 2 * 1024;
      size_t bh = ((size_t)tn * 2 + blk) * 1024;
      ngz0 = Gzr[bzr + gl0];        ngz1 = Gzr[bzr + gl1];
      ngr0 = Gzr[bzr + 1024 + gl0]; ngr1 = Gzr[bzr + 1024 + gl1];
      ngh0 = Gh[bh + gl0];          ngh1 = Gh[bh + gl1];
    }

    // ---- phase 1: z,r = h @ [Uz|Ur]  (A from h_lds, B from registers) ----
    f32x4 az0 = zero4, az1 = zero4, ar0 = zero4, ar1 = zero4;
#pragma unroll
    for (int kt = 0; kt < 8; ++kt) {
      int c = kt * 4 + lh;
      int aoff = (lr * 512 + ((c ^ (lr & 7)) << 4)) >> 1;
      bf16x8 a = *(const bf16x8*)&h_lds[aoff];
      az0 = __builtin_amdgcn_mfma_f32_16x16x32_bf16(a, fragU[0][0][kt], az0, 0, 0, 0);
      az1 = __builtin_amdgcn_mfma_f32_16x16x32_bf16(a, fragU[0][1][kt], az1, 0, 0, 0);
      ar0 = __builtin_amdgcn_mfma_f32_16x16x32_bf16(a, fragU[1][0][kt], ar0, 0, 0, 0);
      ar1 = __builtin_amdgcn_mfma_f32_16x16x32_bf16(a, fragU[1][1][kt], ar1, 0, 0, 0);
    }

    // ---- epilogue 1: sigmoid, r*h -> rh_lds ----
    float zv[2][4];
#pragma unroll
    for (int nt = 0; nt < 2; ++nt) {
      int n = w * 32 + nt * 16 + lr;
#pragma unroll
      for (int q = 0; q < 4; ++q) {
        float accz = nt ? az1[q] : az0[q];
        float accr = nt ? ar1[q] : ar0[q];
        float gzf = bfq(nt ? gz1 : gz0, q);
        float grf = bfq(nt ? gr1 : gr0, q);
        float zf = sigm(accz + gzf);
        float rf = sigm(accr + grf);
        zv[nt][q] = zf;
        float rh = rf * hreg[nt][q];
        int m = m_base + q;
        int byteoff = m * 512 + (((n >> 3) ^ (m & 7)) << 4) + (n & 7) * 2;
        rh_lds[byteoff >> 1] = f2bf(rh);
      }
    }
    __syncthreads();

    // ---- phase 2: hh_acc = (r*h) @ Uh ----
    f32x4 ah0 = zero4, ah1 = zero4;
#pragma unroll
    for (int kt = 0; kt < 8; ++kt) {
      int c = kt * 4 + lh;
      int aoff = (lr * 512 + ((c ^ (lr & 7)) << 4)) >> 1;
      bf16x8 a = *(const bf16x8*)&rh_lds[aoff];
      ah0 = __builtin_amdgcn_mfma_f32_16x16x32_bf16(a, fragU[2][0][kt], ah0, 0, 0, 0);
      ah1 = __builtin_amdgcn_mfma_f32_16x16x32_bf16(a, fragU[2][1][kt], ah1, 0, 0, 0);
    }

    // ---- epilogue 2: tanh, blend, emit h_t ----
#pragma unroll
    for (int nt = 0; nt < 2; ++nt) {
      int n = w * 32 + nt * 16 + lr;
#pragma unroll
      for (int q = 0; q < 4; ++q) {
        float acch = nt ? ah1[q] : ah0[q];
        float ghf = bfq(nt ? gh1 : gh0, q);
        float xh = acch + ghf;
        float e = __expf(-2.f * xh);
        float hh = 2.f * __builtin_amdgcn_rcpf(1.f + e) - 1.f;   // tanh
        float h = hreg[nt][q];
        float hn = h + zv[nt][q] * (hh - h);
        hreg[nt][q] = hn;
        int m = m_base + q;
        int byteoff = m * 512 + (((n >> 3) ^ (m & 7)) << 4) + (n & 7) * 2;
        h_lds[byteoff >> 1] = f2bf(hn);
        hsb[((size_t)m * T_ + t) * H_ + n] = hn;
      }
    }
    gz0 = ngz0; gz1 = ngz1; gr0 = ngr0; gr1 = ngr1; gh0 = ngh0; gh1 = ngh1;
    __syncthreads();
  }
}

// ---------------- Kernel 3: ys = hs @ Wo + bo ------------------------------
__global__ __launch_bounds__(256) void k_out(
    const float* __restrict__ hs, const float* __restrict__ Wo,
    const float* __restrict__ bo, float* __restrict__ ys)
{
  __shared__ __align__(16) float sh[32][H_];
  const int row0 = blockIdx.x * 32;
  const int tid = threadIdx.x;

  const float4* hg = (const float4*)(hs + (size_t)row0 * H_);
  float4* sh4 = (float4*)&sh[0][0];
#pragma unroll
  for (int m = 0; m < 8; ++m) sh4[tid + 256 * m] = hg[tid + 256 * m];
  __syncthreads();

  const int j = tid;
  float acc[32];
#pragma unroll
  for (int i = 0; i < 32; ++i) acc[i] = 0.f;

#pragma unroll 2
  for (int k4 = 0; k4 < H_ / 4; ++k4) {
    float w0 = Wo[(size_t)(4 * k4 + 0) * DOUT + j];
    float w1 = Wo[(size_t)(4 * k4 + 1) * DOUT + j];
    float w2 = Wo[(size_t)(4 * k4 + 2) * DOUT + j];
    float w3 = Wo[(size_t)(4 * k4 + 3) * DOUT + j];
#pragma unroll
    for (int i = 0; i < 32; ++i) {
      float4 hv = *(const float4*)&sh[i][4 * k4];
      acc[i] = fmaf(hv.x, w0, acc[i]);
      acc[i] = fmaf(hv.y, w1, acc[i]);
      acc[i] = fmaf(hv.z, w2, acc[i]);
      acc[i] = fmaf(hv.w, w3, acc[i]);
    }
  }

  const float bj = bo[j];
  float* yp = ys + (size_t)row0 * DOUT + j;
#pragma unroll
  for (int i = 0; i < 32; ++i) yp[(size_t)i * DOUT] = acc[i] + bj;
}

// ---------------------------------------------------------------------------
extern "C" void kernel_launch(void* const* d_in, const int* in_sizes, int n_in,
                              void* d_out, int out_size, void* d_ws, size_t ws_size,
                              hipStream_t stream) {
  const float* x  = (const float*)d_in[0];
  const float* h0 = (const float*)d_in[1];
  const float* Wz = (const float*)d_in[2];
  const float* Uz = (const float*)d_in[3];
  const float* bz = (const float*)d_in[4];
  const float* Wr = (const float*)d_in[5];
  const float* Ur = (const float*)d_in[6];
  const float* br = (const float*)d_in[7];
  const float* Wh = (const float*)d_in[8];
  const float* Uh = (const float*)d_in[9];
  const float* bh = (const float*)d_in[10];
  const float* Wo = (const float*)d_in[11];
  const float* bo = (const float*)d_in[12];

  float* ys = (float*)d_out;
  float* hsO = ys + (size_t)B_ * T_ * DOUT;  // second output, written by scan

  uint2* Gzr = (uint2*)d_out;                // 64 MB, dead until k_out
  uint2* Gh  = (uint2*)d_ws;                 // 32 MB in workspace

  dim3 g1(2048, 3);                          // 256 t-groups x 8 b-groups, 3 gates
  k_gates<<<g1, 256, 0, stream>>>(x, Wz, Wr, Wh, bz, br, bh, Gzr, Gh);
  k_scan<<<2, 512, 0, stream>>>(h0, Uz, Ur, Uh, Gzr, Gh, hsO);
  k_out<<<(B_ * T_) / 32, 256, 0, stream>>>(hsO, Wo, bo, ys);
}

// Round 6
// 5432.375 us; speedup vs baseline: 1.3907x; 1.3907x over previous
//
#include <hip/hip_runtime.h>

#define B_   32
#define T_   2048
#define DIN  128
#define H_   256
#define DOUT 256

typedef float f32x4 __attribute__((ext_vector_type(4)));
typedef short bf16x8 __attribute__((ext_vector_type(8)));

__device__ __forceinline__ unsigned short f2bf(float f) {
  unsigned int u = __builtin_bit_cast(unsigned int, f);
  u += 0x7FFFu + ((u >> 16) & 1u);              // round-to-nearest-even
  return (unsigned short)(u >> 16);
}
// unpack bf16 slot q (0..3) from a uint2 (q0|q1<<16, q2|q3<<16)
__device__ __forceinline__ float bfq(uint2 v, int q) {
  unsigned int u = (q & 2) ? v.y : v.x;
  u = (q & 1) ? (u & 0xFFFF0000u) : (u << 16);
  return __builtin_bit_cast(float, u);
}
__device__ __forceinline__ float sigm(float x) {
  return __builtin_amdgcn_rcpf(1.f + __expf(-x));
}

// ---------------- Kernel 1: G = x @ W + b, packed for the scan's MFMA lanes.
// (unchanged from R5 — validated)
__global__ __launch_bounds__(256) void k_gates(
    const float* __restrict__ x,
    const float* __restrict__ Wz, const float* __restrict__ Wr,
    const float* __restrict__ Wh,
    const float* __restrict__ bz, const float* __restrict__ br,
    const float* __restrict__ bh,
    uint2* __restrict__ Gzr, uint2* __restrict__ Gh)
{
  __shared__ __align__(16) float sx[32][DIN];
  const int gate = blockIdx.y;
  const float* W = (gate == 0) ? Wz : (gate == 1) ? Wr : Wh;
  const float* bias = (gate == 0) ? bz : (gate == 1) ? br : bh;
  const int tg = blockIdx.x & 255;   // t-group
  const int bg = blockIdx.x >> 8;    // b-group 0..7
  const int t0 = tg * 8, b0 = bg * 4;
  const int tid = threadIdx.x;

  {
    const float4* x4 = (const float4*)x;
    float4* s4 = (float4*)&sx[0][0];
#pragma unroll
    for (int mm = 0; mm < 4; ++mm) {
      int idx = tid + 256 * mm;      // 0..1023
      int i = idx >> 5, c4 = idx & 31;
      int Ri = (b0 + (i >> 3)) * T_ + t0 + (i & 7);
      s4[idx] = x4[(size_t)Ri * 32 + c4];
    }
  }
  __syncthreads();

  const int j = tid;
  const float bj = bias[j];
  float acc[32];
#pragma unroll
  for (int i = 0; i < 32; ++i) acc[i] = 0.f;

#pragma unroll 2
  for (int k4 = 0; k4 < DIN / 4; ++k4) {
    float w0 = W[(size_t)(4 * k4 + 0) * H_ + j];
    float w1 = W[(size_t)(4 * k4 + 1) * H_ + j];
    float w2 = W[(size_t)(4 * k4 + 2) * H_ + j];
    float w3 = W[(size_t)(4 * k4 + 3) * H_ + j];
#pragma unroll
    for (int i = 0; i < 32; ++i) {
      float4 xv = *(const float4*)&sx[i][4 * k4];
      acc[i] = fmaf(xv.x, w0, acc[i]);
      acc[i] = fmaf(xv.y, w1, acc[i]);
      acc[i] = fmaf(xv.z, w2, acc[i]);
      acc[i] = fmaf(xv.w, w3, acc[i]);
    }
  }

  const int w = j >> 5, nt = (j >> 4) & 1;
  const int l = (bg & 3) * 16 + (j & 15);
  const int blk = bg >> 2;
#pragma unroll
  for (int ti = 0; ti < 8; ++ti) {
    int t = t0 + ti;
    unsigned int q0 = f2bf(acc[0 * 8 + ti] + bj);
    unsigned int q1 = f2bf(acc[1 * 8 + ti] + bj);
    unsigned int q2 = f2bf(acc[2 * 8 + ti] + bj);
    unsigned int q3 = f2bf(acc[3 * 8 + ti] + bj);
    uint2 v;
    v.x = q0 | (q1 << 16);
    v.y = q2 | (q3 << 16);
    if (gate < 2) {
      size_t idx = ((((size_t)t * 2 + blk) * 2 + gate) * 16 + (w * 2 + nt)) * 64 + l;
      Gzr[idx] = v;
    } else {
      size_t idx = (((size_t)t * 2 + blk) * 16 + (w * 2 + nt)) * 64 + l;
      Gh[idx] = v;
    }
  }
}

// ---------------- Kernel 2: MFMA GRU scan. 2 blocks x 16 batches. ----------
// 512 threads = 8 waves. LDS = 144KB -> exactly 1 block/CU -> occupancy
// ceiling 2 waves/SIMD -> 256-VGPR budget for the allocator.
// Register fragments: Uz, Ur only (128 VGPRs). Uh lives in LDS, pre-packed
// in B-fragment order, streamed via ds_read_b128 in phase 2.
__global__
__attribute__((amdgpu_flat_work_group_size(512, 512), amdgpu_waves_per_eu(1, 2)))
void k_scan(
    const float* __restrict__ h0,
    const float* __restrict__ Uz, const float* __restrict__ Ur,
    const float* __restrict__ Uh,
    const uint2* __restrict__ Gzr, const uint2* __restrict__ Gh,
    float* __restrict__ hs)
{
  // Uh as B-fragments: frag (w,nt,kt) at [((w*2+nt)*8+kt)*512 + l*8 + e]
  __shared__ __align__(16) unsigned short uh_lds[8 * 2 * 8 * 512 / 8 * 8];  // 65536 bf16 = 128KB
  __shared__ __align__(16) unsigned short h_lds[16 * 256];                  // 8KB
  __shared__ __align__(16) unsigned short rh_lds[16 * 256];                 // 8KB

  const int blk = blockIdx.x;        // 0..1
  const int tid = threadIdx.x;
  const int w = tid >> 6;            // wave 0..7
  const int l = tid & 63;
  const int lr = l & 15;             // A-row / col-low selector
  const int lh = l >> 4;             // 0..3 (k-group / m-group)
  const int m_base = lh * 4;

  // ---- pack Uh into LDS B-fragment layout (one-time) ----
  for (int idx = tid; idx < 8 * 2 * 8 * 64; idx += 512) {
    int ll = idx & 63;
    int kt = (idx >> 6) & 7;
    int nt = (idx >> 9) & 1;
    int ww = idx >> 10;
    int n = ww * 32 + nt * 16 + (ll & 15);
    int k0 = kt * 32 + (ll >> 4) * 8;
    bf16x8 f;
#pragma unroll
    for (int e = 0; e < 8; ++e)
      f[e] = (short)f2bf(Uh[(size_t)(k0 + e) * H_ + n]);
    *(bf16x8*)&uh_lds[(size_t)idx * 8] = f;
  }

  // ---- B fragments for Uz, Ur: fragU[gate][nt][kt] (128 VGPRs) ----
  bf16x8 fragU[2][2][8];
  {
    const float* Us[2] = {Uz, Ur};
#pragma unroll
    for (int g = 0; g < 2; ++g) {
#pragma unroll
      for (int nt = 0; nt < 2; ++nt) {
        int n = w * 32 + nt * 16 + lr;
#pragma unroll
        for (int kt = 0; kt < 8; ++kt) {
          int k0 = kt * 32 + lh * 8;
          bf16x8 f;
#pragma unroll
          for (int e = 0; e < 8; ++e)
            f[e] = (short)f2bf(Us[g][(size_t)(k0 + e) * H_ + n]);
          fragU[g][nt][kt] = f;
        }
      }
    }
  }

  // ---- init h-state (C-layout registers) + h_lds (swizzled bf16) ----
  float hreg[2][4];
#pragma unroll
  for (int nt = 0; nt < 2; ++nt) {
    int n = w * 32 + nt * 16 + lr;
#pragma unroll
    for (int q = 0; q < 4; ++q) {
      int m = m_base + q;
      float h = h0[(size_t)(blk * 16 + m) * H_ + n];
      hreg[nt][q] = h;
      int byteoff = m * 512 + ((((n >> 3) ^ (m & 7)) << 4)) + (n & 7) * 2;
      h_lds[byteoff >> 1] = f2bf(h);
    }
  }
  __syncthreads();

  // ---- G: load t=0, prefetch one step ahead inside the loop ----
  const size_t gl0 = (size_t)(w * 2 + 0) * 64 + l;
  const size_t gl1 = (size_t)(w * 2 + 1) * 64 + l;
  uint2 gz0, gz1, gr0, gr1, gh0, gh1;
  {
    size_t bzr = ((size_t)0 * 2 + blk) * 2 * 1024;
    size_t bh = ((size_t)0 * 2 + blk) * 1024;
    gz0 = Gzr[bzr + gl0];        gz1 = Gzr[bzr + gl1];
    gr0 = Gzr[bzr + 1024 + gl0]; gr1 = Gzr[bzr + 1024 + gl1];
    gh0 = Gh[bh + gl0];          gh1 = Gh[bh + gl1];
  }

  float* hsb = hs + (size_t)(blk * 16) * T_ * H_;
  const f32x4 zero4 = {0.f, 0.f, 0.f, 0.f};
  const unsigned short* uhw = &uh_lds[(size_t)w * 16 * 512];  // wave's Uh base

#pragma unroll 1
  for (int t = 0; t < T_; ++t) {
    // prefetch next step's G (independent of everything this step)
    uint2 ngz0, ngz1, ngr0, ngr1, ngh0, ngh1;
    {
      int tn = (t + 1 < T_) ? (t + 1) : t;
      size_t bzr = ((size_t)tn * 2 + blk) * 2 * 1024;
      size_t bh = ((size_t)tn * 2 + blk) * 1024;
      ngz0 = Gzr[bzr + gl0];        ngz1 = Gzr[bzr + gl1];
      ngr0 = Gzr[bzr + 1024 + gl0]; ngr1 = Gzr[bzr + 1024 + gl1];
      ngh0 = Gh[bh + gl0];          ngh1 = Gh[bh + gl1];
    }

    // ---- phase 1: z,r = h @ [Uz|Ur]  (A from h_lds, B from registers) ----
    f32x4 az0 = zero4, az1 = zero4, ar0 = zero4, ar1 = zero4;
#pragma unroll
    for (int kt = 0; kt < 8; ++kt) {
      int c = kt * 4 + lh;
      int aoff = (lr * 512 + ((c ^ (lr & 7)) << 4)) >> 1;
      bf16x8 a = *(const bf16x8*)&h_lds[aoff];
      az0 = __builtin_amdgcn_mfma_f32_16x16x32_bf16(a, fragU[0][0][kt], az0, 0, 0, 0);
      az1 = __builtin_amdgcn_mfma_f32_16x16x32_bf16(a, fragU[0][1][kt], az1, 0, 0, 0);
      ar0 = __builtin_amdgcn_mfma_f32_16x16x32_bf16(a, fragU[1][0][kt], ar0, 0, 0, 0);
      ar1 = __builtin_amdgcn_mfma_f32_16x16x32_bf16(a, fragU[1][1][kt], ar1, 0, 0, 0);
    }

    // ---- epilogue 1: sigmoid, r*h -> rh_lds ----
    float zv[2][4];
#pragma unroll
    for (int nt = 0; nt < 2; ++nt) {
      int n = w * 32 + nt * 16 + lr;
#pragma unroll
      for (int q = 0; q < 4; ++q) {
        float accz = nt ? az1[q] : az0[q];
        float accr = nt ? ar1[q] : ar0[q];
        float gzf = bfq(nt ? gz1 : gz0, q);
        float grf = bfq(nt ? gr1 : gr0, q);
        float zf = sigm(accz + gzf);
        float rf = sigm(accr + grf);
        zv[nt][q] = zf;
        float rh = rf * hreg[nt][q];
        int m = m_base + q;
        int byteoff = m * 512 + (((n >> 3) ^ (m & 7)) << 4) + (n & 7) * 2;
        rh_lds[byteoff >> 1] = f2bf(rh);
      }
    }
    __syncthreads();

    // ---- phase 2: hh_acc = (r*h) @ Uh  (A from rh_lds, B from uh_lds) ----
    f32x4 ah0 = zero4, ah1 = zero4;
#pragma unroll
    for (int kt = 0; kt < 8; ++kt) {
      int c = kt * 4 + lh;
      int aoff = (lr * 512 + ((c ^ (lr & 7)) << 4)) >> 1;
      bf16x8 a = *(const bf16x8*)&rh_lds[aoff];
      bf16x8 b0 = *(const bf16x8*)&uhw[(size_t)(0 * 8 + kt) * 512 + l * 8];
      bf16x8 b1 = *(const bf16x8*)&uhw[(size_t)(1 * 8 + kt) * 512 + l * 8];
      ah0 = __builtin_amdgcn_mfma_f32_16x16x32_bf16(a, b0, ah0, 0, 0, 0);
      ah1 = __builtin_amdgcn_mfma_f32_16x16x32_bf16(a, b1, ah1, 0, 0, 0);
    }

    // ---- epilogue 2: tanh, blend, emit h_t ----
#pragma unroll
    for (int nt = 0; nt < 2; ++nt) {
      int n = w * 32 + nt * 16 + lr;
#pragma unroll
      for (int q = 0; q < 4; ++q) {
        float acch = nt ? ah1[q] : ah0[q];
        float ghf = bfq(nt ? gh1 : gh0, q);
        float xh = acch + ghf;
        float e = __expf(-2.f * xh);
        float hh = 2.f * __builtin_amdgcn_rcpf(1.f + e) - 1.f;   // tanh
        float h = hreg[nt][q];
        float hn = h + zv[nt][q] * (hh - h);
        hreg[nt][q] = hn;
        int m = m_base + q;
        int byteoff = m * 512 + (((n >> 3) ^ (m & 7)) << 4) + (n & 7) * 2;
        h_lds[byteoff >> 1] = f2bf(hn);
        hsb[((size_t)m * T_ + t) * H_ + n] = hn;
      }
    }
    gz0 = ngz0; gz1 = ngz1; gr0 = ngr0; gr1 = ngr1; gh0 = ngh0; gh1 = ngh1;
    __syncthreads();
  }
}

// ---------------- Kernel 3: ys = hs @ Wo + bo ------------------------------
__global__ __launch_bounds__(256) void k_out(
    const float* __restrict__ hs, const float* __restrict__ Wo,
    const float* __restrict__ bo, float* __restrict__ ys)
{
  __shared__ __align__(16) float sh[32][H_];
  const int row0 = blockIdx.x * 32;
  const int tid = threadIdx.x;

  const float4* hg = (const float4*)(hs + (size_t)row0 * H_);
  float4* sh4 = (float4*)&sh[0][0];
#pragma unroll
  for (int m = 0; m < 8; ++m) sh4[tid + 256 * m] = hg[tid + 256 * m];
  __syncthreads();

  const int j = tid;
  float acc[32];
#pragma unroll
  for (int i = 0; i < 32; ++i) acc[i] = 0.f;

#pragma unroll 2
  for (int k4 = 0; k4 < H_ / 4; ++k4) {
    float w0 = Wo[(size_t)(4 * k4 + 0) * DOUT + j];
    float w1 = Wo[(size_t)(4 * k4 + 1) * DOUT + j];
    float w2 = Wo[(size_t)(4 * k4 + 2) * DOUT + j];
    float w3 = Wo[(size_t)(4 * k4 + 3) * DOUT + j];
#pragma unroll
    for (int i = 0; i < 32; ++i) {
      float4 hv = *(const float4*)&sh[i][4 * k4];
      acc[i] = fmaf(hv.x, w0, acc[i]);
      acc[i] = fmaf(hv.y, w1, acc[i]);
      acc[i] = fmaf(hv.z, w2, acc[i]);
      acc[i] = fmaf(hv.w, w3, acc[i]);
    }
  }

  const float bj = bo[j];
  float* yp = ys + (size_t)row0 * DOUT + j;
#pragma unroll
  for (int i = 0; i < 32; ++i) yp[(size_t)i * DOUT] = acc[i] + bj;
}

// ---------------------------------------------------------------------------
extern "C" void kernel_launch(void* const* d_in, const int* in_sizes, int n_in,
                              void* d_out, int out_size, void* d_ws, size_t ws_size,
                              hipStream_t stream) {
  const float* x  = (const float*)d_in[0];
  const float* h0 = (const float*)d_in[1];
  const float* Wz = (const float*)d_in[2];
  const float* Uz = (const float*)d_in[3];
  const float* bz = (const float*)d_in[4];
  const float* Wr = (const float*)d_in[5];
  const float* Ur = (const float*)d_in[6];
  const float* br = (const float*)d_in[7];
  const float* Wh = (const float*)d_in[8];
  const float* Uh = (const float*)d_in[9];
  const float* bh = (const float*)d_in[10];
  const float* Wo = (const float*)d_in[11];
  const float* bo = (const float*)d_in[12];

  float* ys = (float*)d_out;
  float* hsO = ys + (size_t)B_ * T_ * DOUT;  // second output, written by scan

  uint2* Gzr = (uint2*)d_out;                // 64 MB, dead until k_out
  uint2* Gh  = (uint2*)d_ws;                 // 32 MB in workspace

  dim3 g1(2048, 3);                          // 256 t-groups x 8 b-groups, 3 gates
  k_gates<<<g1, 256, 0, stream>>>(x, Wz, Wr, Wh, bz, br, bh, Gzr, Gh);
  k_scan<<<2, 512, 0, stream>>>(h0, Uz, Ur, Uh, Gzr, Gh, hsO);
  k_out<<<(B_ * T_) / 32, 256, 0, stream>>>(hsO, Wo, bo, ys);
}